// Round 1
// baseline (81.830 us; speedup 1.0000x reference)
//
#include <hip/hip_runtime.h>

// RBFNN L1-distance, round 3: DMA-staged f16 pipeline.
// k_cvt: one-shot f32->f16 convert of X (1 MB) and C (0.5 MB) into workspace.
// k_sim: 1024 blocks x 64 threads (1 wave), tile 16x32, 8 outputs/thread
//   (rows tr*4..+3, cols {tc, tc+16}). Staging via global_load_lds dwordx4
//   (6 DMA/chunk, no register round-trip, no staging VALU), 3-deep LDS
//   buffer rotation, counted s_waitcnt vmcnt(6) so 6 loads stay in flight
//   across every chunk. No __syncthreads anywhere (single-wave blocks).
//   LDS image is the linear DMA layout; per-lane GLOBAL source addresses are
//   pre-swizzled (rule #21) so ds_read_b128 fragments see only 2-way bank
//   aliasing (free per m136). ds_read offsets are compile-time immediates.
// k_out: reduce 1024 block maxes in-wave, out = beta*(max*1.001 - sim).

typedef _Float16 h2 __attribute__((ext_vector_type(2)));
typedef float f4 __attribute__((ext_vector_type(4)));
typedef unsigned int u32;
typedef unsigned int u32x4 __attribute__((ext_vector_type(4)));
typedef unsigned int u32x2 __attribute__((ext_vector_type(2)));
typedef unsigned short u16;

#define DIM_O 512
#define DIM_K 512
#define W_DIST 1.001f

__device__ __forceinline__ h2 as_h2(u32 u){ h2 r; __builtin_memcpy(&r,&u,4); return r; }
__device__ __forceinline__ u32 as_u(h2 h){ u32 r; __builtin_memcpy(&r,&h,4); return r; }
__device__ __forceinline__ u32 cvt2(float a, float b){
    auto h = __builtin_amdgcn_cvt_pkrtz(a, b);
    u32 r; __builtin_memcpy(&r, &h, 4); return r;
}

__device__ __forceinline__ void gload16(const void* g, void* l) {
    __builtin_amdgcn_global_load_lds(
        (const __attribute__((address_space(1))) u32*)g,
        (__attribute__((address_space(3))) u32*)l, 16, 0, 0);
}

// ---------------- k_cvt: f32 -> f16 (packed) ----------------
// 768 blocks x 256 thr: blocks 0..511 convert X (131072 f4), 512..767 convert C (65536 f4).
__global__ __launch_bounds__(256) void k_cvt(const float* __restrict__ X,
                                             const float* __restrict__ C,
                                             u32x2* __restrict__ Xh,
                                             u32x2* __restrict__ Ch)
{
    const int f = blockIdx.x * 256 + threadIdx.x;
    const int NX = (1024 * DIM_K) / 4;
    f4 v;
    if (f < NX) v = *(const f4*)(X + 4 * f);
    else        v = *(const f4*)(C + 4 * (f - NX));
    u32x2 w; w[0] = cvt2(v.x, v.y); w[1] = cvt2(v.z, v.w);
    if (f < NX) Xh[f] = w; else Ch[f - NX] = w;
}

// ---------------- k_sim ----------------
// LDS buffer layout (per 6144 B slot): X tile 16x64 f16 = 2048 B (2 DMA),
// C tile 32x64 f16 = 4096 B (4 DMA). DMA writes lane l -> slot + i*1024 + l*16.
// Source swizzle chosen so reads are:
//   X row r, k-group g (8 f16): byte = (g>>2)*1024 + (g&3)*256 + r*16
//   C col c, k-group g        : byte = 2048 + (g>>1)*1024 + (g&1)*512 + c*16
__global__ __launch_bounds__(64) void k_sim(const u16* __restrict__ Xh,
                                            const u16* __restrict__ Ch,
                                            float* __restrict__ S,
                                            float* __restrict__ bmax)
{
    __shared__ __align__(16) char lds[3 * 6144];
    const int tid = threadIdx.x;
    const int bx = blockIdx.x & 15;   // 16 col tiles (512/32)
    const int by = blockIdx.x >> 4;   // 64 row tiles (1024/16)
    const int row0 = by * 16, col0 = bx * 32;
    const int tr = tid >> 4;          // 0..3 -> rows tr*4..tr*4+3
    const int tc = tid & 15;          // 0..15 -> cols tc, tc+16

    // per-lane DMA source addresses (pre-swizzled to match linear LDS image):
    // X instr i, lane l reads row (l&15), k = (l>>4)*8 + i*32  [+ t*64 per chunk]
    // C instr i, lane l reads row (l&31), k = (l>>5)*8 + i*16  [+ t*64 per chunk]
    const char* xsrc = (const char*)(Xh + (row0 + (tid & 15)) * DIM_K + (tid >> 4) * 8);
    const char* csrc = (const char*)(Ch + (col0 + (tid & 31)) * DIM_K + (tid >> 5) * 8);

    char* b0 = lds;           // buffer holding chunk t
    char* b1 = lds + 6144;    // chunk t+1 (in flight)
    char* b2 = lds + 12288;   // stage target for chunk t+2

    auto stage = [&](int q, char* p) {
        const char* xq = xsrc + q * 128;   // 64 f16 per chunk
        const char* cq = csrc + q * 128;
        gload16(xq,      p);
        gload16(xq + 64, p + 1024);
        gload16(cq,      p + 2048);
        gload16(cq + 32, p + 3072);
        gload16(cq + 64, p + 4096);
        gload16(cq + 96, p + 5120);
    };

    float acc[4][2] = {};
    const h2 one2 = {(_Float16)1.f, (_Float16)1.f};

    stage(0, b0);
    stage(1, b1);

    for (int t = 0; t < 8; ++t) {
        // chunk t's 6 loads are the oldest; keep chunk t+1's 6 in flight.
        if (t < 7) { asm volatile("s_waitcnt vmcnt(6)" ::: "memory"); }
        else       { asm volatile("s_waitcnt vmcnt(0)" ::: "memory"); }
        __builtin_amdgcn_sched_barrier(0);
        if (t < 6) stage(t + 2, b2);   // different buffer than the one being read

        const char* xb = b0;
        const char* cb = b0 + 2048;
#pragma unroll
        for (int g = 0; g < 8; ++g) {
            const int xo = (g >> 2) * 1024 + (g & 3) * 256 + tr * 64;
            const int co = (g >> 1) * 1024 + (g & 1) * 512 + tc * 16;
            u32x4 xr[4]; u32x4 cr[2];
            xr[0] = *(const u32x4*)(xb + xo);
            xr[1] = *(const u32x4*)(xb + xo + 16);
            xr[2] = *(const u32x4*)(xb + xo + 32);
            xr[3] = *(const u32x4*)(xb + xo + 48);
            cr[0] = *(const u32x4*)(cb + co);
            cr[1] = *(const u32x4*)(cb + co + 256);
#pragma unroll
            for (int k2 = 0; k2 < 4; ++k2) {
#pragma unroll
                for (int i = 0; i < 4; ++i) {
                    h2 a = as_h2(xr[i][k2]);
#pragma unroll
                    for (int j = 0; j < 2; ++j) {
                        h2 d = a - as_h2(cr[j][k2]);           // v_pk_sub_f16
                        h2 ad = as_h2(as_u(d) & 0x7fff7fffu);  // abs both halves
                        acc[i][j] = __builtin_amdgcn_fdot2(ad, one2, acc[i][j], false);
                    }
                }
            }
        }
        char* tmp = b0; b0 = b1; b1 = b2; b2 = tmp;
    }

    // epilogue: store sim + block max
    float m = 0.f;
#pragma unroll
    for (int i = 0; i < 4; ++i) {
        const int r = row0 + tr * 4 + i;
        S[r * DIM_O + col0 + tc]      = acc[i][0];
        S[r * DIM_O + col0 + tc + 16] = acc[i][1];
        m = fmaxf(m, fmaxf(acc[i][0], acc[i][1]));
    }
#pragma unroll
    for (int off = 32; off > 0; off >>= 1)
        m = fmaxf(m, __shfl_xor(m, off, 64));
    if (tid == 0) bmax[blockIdx.x] = m;
}

// ---------------- k_out ----------------
__global__ __launch_bounds__(256) void k_out(float* __restrict__ S,
                                             const float* __restrict__ beta,
                                             const float* __restrict__ bmax)
{
    const int tid = threadIdx.x;
    const int lane = tid & 63;
    float m = 0.f;
#pragma unroll
    for (int i = 0; i < 16; ++i) // 1024 block maxes
        m = fmaxf(m, bmax[lane + 64 * i]);
#pragma unroll
    for (int off = 32; off > 0; off >>= 1)
        m = fmaxf(m, __shfl_xor(m, off, 64));
    const float shift = m * W_DIST;

    const int f = blockIdx.x * 256 + tid; // float4 index, 131072 total
    f4 s = ((const f4*)S)[f];
    f4 b = ((const f4*)beta)[f & 127];
    f4 r;
    r.x = b.x * (shift - s.x);
    r.y = b.y * (shift - s.y);
    r.z = b.z * (shift - s.z);
    r.w = b.w * (shift - s.w);
    ((f4*)S)[f] = r;
}

extern "C" void kernel_launch(void* const* d_in, const int* in_sizes, int n_in,
                              void* d_out, int out_size, void* d_ws, size_t ws_size,
                              hipStream_t stream) {
    const float* X = (const float*)d_in[0];
    const float* C = (const float*)d_in[1];
    const float* beta = (const float*)d_in[2];
    float* S = (float*)d_out;     // sim staged in d_out, transformed in place
    float* bmax = (float*)d_ws;   // 1024 floats scratch
    u16* Xh = (u16*)((char*)d_ws + 4096);
    u16* Ch = (u16*)((char*)d_ws + 4096 + 1024 * 1024);
    k_cvt<<<768, 256, 0, stream>>>(X, C, (u32x2*)Xh, (u32x2*)Ch);
    k_sim<<<1024, 64, 0, stream>>>(Xh, Ch, S, bmax);
    k_out<<<512, 256, 0, stream>>>(S, beta, bmax);
}

// Round 2
// 80.606 us; speedup vs baseline: 1.0152x; 1.0152x over previous
//
#include <hip/hip_runtime.h>

// RBFNN L1-distance, round 4: 2-dispatch fused pipeline.
// Window decomposition (from fill Dispatch_Id spacing = 40/iter):
//   ~40.5 us unconditional 256 MiB ws re-poison fill (harness)
//   ~35   us ~36 reset memset dispatches (harness)
//   ~8    us our kernels  <- the only controllable slice
// So: minimize dispatch count (2) and kernel time.
// k_sim: 1024 blocks x 64 threads (single wave). Tile 16x32, 8 outputs/thread
//   (rows tr*4..+3, cols {tc, tc+16}). Per chunk (64 k): 12 f4 global loads
//   (prefetched 1 chunk ahead, fly under the 1536-cycle compute), 24
//   v_cvt_pkrtz f32->f16x2, 6 ds_write_b128 (2-way banked = free), then
//   8 groups x 6 ds_read_b128 (X reads broadcast, C reads 2-way) feeding
//   v_pk_sub_f16 + v_and(abs) + v_dot2_f32_f16 (1.5 instr/pair, f32 accum).
//   NO __syncthreads anywhere: single-wave block, DS ops execute in wave
//   program order; compiler inserts lgkmcnt between write burst and reads.
//   Single 6 KB LDS buffer (reads of chunk t precede writes of t+1 in
//   program order -> no double buffer needed).
// k_out: reduce 1024 block maxes in-wave, out = beta*(max*1.001 - sim).

typedef _Float16 h2 __attribute__((ext_vector_type(2)));
typedef float f4 __attribute__((ext_vector_type(4)));
typedef unsigned int u32;
typedef unsigned int u32x4 __attribute__((ext_vector_type(4)));

#define DIM_O 512
#define DIM_K 512
#define W_DIST 1.001f

__device__ __forceinline__ h2 as_h2(u32 u){ h2 r; __builtin_memcpy(&r,&u,4); return r; }
__device__ __forceinline__ u32 as_u(h2 h){ u32 r; __builtin_memcpy(&r,&h,4); return r; }
__device__ __forceinline__ u32 cvt2(float a, float b){
    auto h = __builtin_amdgcn_cvt_pkrtz(a, b);
    u32 r; __builtin_memcpy(&r, &h, 4); return r;
}

// ---------------- k_sim ----------------
// LDS image (6144 B): X tile 16x64 f16 = 2048 B (2 slabs of 1024), C tile
// 32x64 f16 = 4096 B (4 slabs). Slab i, lane l holds 16 B at i*1024 + l*16.
//   X slab i, lane l = row (l&15), k = (l>>4)*8 + i*32 .. +8
//   C slab i, lane l = col (l&31), k = (l>>5)*8 + i*16 .. +8
// Read addressing (immediate offsets):
//   X row r, k-group g (8 f16): byte = (g>>2)*1024 + (g&3)*256 + r*16
//   C col c, k-group g        : byte = 2048 + (g>>1)*1024 + (g&1)*512 + c*16
__global__ __launch_bounds__(64) void k_sim(const float* __restrict__ X,
                                            const float* __restrict__ C,
                                            float* __restrict__ S,
                                            float* __restrict__ bmax)
{
    __shared__ __align__(16) char lds[6144];
    const int tid = threadIdx.x;
    const int bx = blockIdx.x & 15;   // 16 col tiles (512/32)
    const int by = blockIdx.x >> 4;   // 64 row tiles (1024/16)
    const int row0 = by * 16, col0 = bx * 32;
    const int tr = tid >> 4;          // 0..3 -> rows tr*4..tr*4+3
    const int tc = tid & 15;          // 0..15 -> cols tc, tc+16

    // per-lane f32 source bases matching the LDS image above
    const float* xsrc = X + (row0 + (tid & 15)) * DIM_K + (tid >> 4) * 8;
    const float* csrc = C + (col0 + (tid & 31)) * DIM_K + (tid >> 5) * 8;
    char* xdst = lds + tid * 16;          // + i*1024
    char* cdst = lds + 2048 + tid * 16;   // + i*1024

    f4 xv[4], cv[8];  // prefetch regs: xv[2i+h] = floats (l>>4)*8 + i*32 + h*4..
    auto loadc = [&](int t) {
        const float* xq = xsrc + t * 64;
        const float* cq = csrc + t * 64;
#pragma unroll
        for (int i = 0; i < 2; ++i)
#pragma unroll
            for (int h = 0; h < 2; ++h)
                xv[2 * i + h] = *(const f4*)(xq + i * 32 + h * 4);
#pragma unroll
        for (int i = 0; i < 4; ++i)
#pragma unroll
            for (int h = 0; h < 2; ++h)
                cv[2 * i + h] = *(const f4*)(cq + i * 16 + h * 4);
    };

    float acc[4][2] = {};
    const h2 one2 = {(_Float16)1.f, (_Float16)1.f};

    loadc(0);

    for (int t = 0; t < 8; ++t) {
        // cvt + stage current chunk (consumes xv/cv -> frees them for prefetch)
#pragma unroll
        for (int i = 0; i < 2; ++i) {
            u32x4 w;
            w[0] = cvt2(xv[2 * i].x,     xv[2 * i].y);
            w[1] = cvt2(xv[2 * i].z,     xv[2 * i].w);
            w[2] = cvt2(xv[2 * i + 1].x, xv[2 * i + 1].y);
            w[3] = cvt2(xv[2 * i + 1].z, xv[2 * i + 1].w);
            *(u32x4*)(xdst + i * 1024) = w;
        }
#pragma unroll
        for (int i = 0; i < 4; ++i) {
            u32x4 w;
            w[0] = cvt2(cv[2 * i].x,     cv[2 * i].y);
            w[1] = cvt2(cv[2 * i].z,     cv[2 * i].w);
            w[2] = cvt2(cv[2 * i + 1].x, cv[2 * i + 1].y);
            w[3] = cvt2(cv[2 * i + 1].z, cv[2 * i + 1].w);
            *(u32x4*)(cdst + i * 1024) = w;
        }
        if (t < 7) loadc(t + 1);   // issue next chunk; flies under compute

        // compute: 8 groups of 8 k (4 h2) each; all reads b128, imm offsets
#pragma unroll
        for (int g = 0; g < 8; ++g) {
            const int xo = (g >> 2) * 1024 + (g & 3) * 256 + tr * 64;
            const int co = 2048 + (g >> 1) * 1024 + (g & 1) * 512 + tc * 16;
            u32x4 xr[4], cr[2];
            xr[0] = *(const u32x4*)(lds + xo);
            xr[1] = *(const u32x4*)(lds + xo + 16);
            xr[2] = *(const u32x4*)(lds + xo + 32);
            xr[3] = *(const u32x4*)(lds + xo + 48);
            cr[0] = *(const u32x4*)(lds + co);
            cr[1] = *(const u32x4*)(lds + co + 256);
#pragma unroll
            for (int k2 = 0; k2 < 4; ++k2) {
#pragma unroll
                for (int i = 0; i < 4; ++i) {
                    h2 a = as_h2(xr[i][k2]);
#pragma unroll
                    for (int j = 0; j < 2; ++j) {
                        h2 d = a - as_h2(cr[j][k2]);           // v_pk_sub_f16
                        h2 ad = as_h2(as_u(d) & 0x7fff7fffu);  // abs both halves
                        acc[i][j] = __builtin_amdgcn_fdot2(ad, one2, acc[i][j], false);
                    }
                }
            }
        }
    }

    // epilogue: store sim + block max
    float m = 0.f;
#pragma unroll
    for (int i = 0; i < 4; ++i) {
        const int r = row0 + tr * 4 + i;
        S[r * DIM_O + col0 + tc]      = acc[i][0];
        S[r * DIM_O + col0 + tc + 16] = acc[i][1];
        m = fmaxf(m, fmaxf(acc[i][0], acc[i][1]));
    }
#pragma unroll
    for (int off = 32; off > 0; off >>= 1)
        m = fmaxf(m, __shfl_xor(m, off, 64));
    if (tid == 0) bmax[blockIdx.x] = m;
}

// ---------------- k_out ----------------
__global__ __launch_bounds__(256) void k_out(float* __restrict__ S,
                                             const float* __restrict__ beta,
                                             const float* __restrict__ bmax)
{
    const int tid = threadIdx.x;
    const int lane = tid & 63;
    float m = 0.f;
#pragma unroll
    for (int i = 0; i < 16; ++i) // 1024 block maxes
        m = fmaxf(m, bmax[lane + 64 * i]);
#pragma unroll
    for (int off = 32; off > 0; off >>= 1)
        m = fmaxf(m, __shfl_xor(m, off, 64));
    const float shift = m * W_DIST;

    const int f = blockIdx.x * 256 + tid; // float4 index, 131072 total
    f4 s = ((const f4*)S)[f];
    f4 b = ((const f4*)beta)[f & 127];
    f4 r;
    r.x = b.x * (shift - s.x);
    r.y = b.y * (shift - s.y);
    r.z = b.z * (shift - s.z);
    r.w = b.w * (shift - s.w);
    ((f4*)S)[f] = r;
}

extern "C" void kernel_launch(void* const* d_in, const int* in_sizes, int n_in,
                              void* d_out, int out_size, void* d_ws, size_t ws_size,
                              hipStream_t stream) {
    const float* X = (const float*)d_in[0];
    const float* C = (const float*)d_in[1];
    const float* beta = (const float*)d_in[2];
    float* S = (float*)d_out;     // sim staged in d_out, transformed in place
    float* bmax = (float*)d_ws;   // 1024 floats scratch
    k_sim<<<1024, 64, 0, stream>>>(X, C, S, bmax);
    k_out<<<512, 256, 0, stream>>>(S, beta, bmax);
}